// Round 2
// baseline (140.685 us; speedup 1.0000x reference)
//
#include <hip/hip_runtime.h>

constexpr int BLK = 256;
constexpr int EPT = 4;   // edges per thread

struct F3 { float x, y, z; };
struct F4 { float x, y, z, w; };

__device__ __forceinline__ F3 cross3(const F3 a, const F3 b) {
    return { a.y * b.z - a.z * b.y,
             a.z * b.x - a.x * b.z,
             a.x * b.y - a.y * b.x };
}

// v + w*t + cross(qv, t), t = 2*cross(qv, v)   (matches _qrot)
__device__ __forceinline__ F3 qrot(const F4 q, const F3 v) {
    F3 qv{ q.x, q.y, q.z };
    F3 t = cross3(qv, v);
    t.x *= 2.f; t.y *= 2.f; t.z *= 2.f;
    F3 c = cross3(qv, t);
    return { v.x + q.w * t.x + c.x,
             v.y + q.w * t.y + c.y,
             v.z + q.w * t.z + c.z };
}

// (x,y,z,w) layout, matches _qmul
__device__ __forceinline__ F4 qmul(const F4 a, const F4 b) {
    return { a.w * b.x + a.x * b.w + a.y * b.z - a.z * b.y,
             a.w * b.y - a.x * b.z + a.y * b.w + a.z * b.x,
             a.w * b.z + a.x * b.y - a.y * b.x + a.z * b.w,
             a.w * b.w - a.x * b.x - a.y * b.y - a.z * b.z };
}

__device__ __forceinline__ void edge_compute(const F3 tp, const F4 qp,
                                             const float* __restrict__ n1,
                                             const float* __restrict__ n2,
                                             float* __restrict__ o)
{
    F3 t1{ n1[0], n1[1], n1[2] };
    F4 q1{ n1[3], n1[4], n1[5], n1[6] };
    F3 t2{ n2[0], n2[1], n2[2] };
    F4 q2{ n2[3], n2[4], n2[5], n2[6] };

    // inv(node1)
    F4 qi{ -q1.x, -q1.y, -q1.z, q1.w };
    F3 ti = qrot(qi, t1);
    ti.x = -ti.x; ti.y = -ti.y; ti.z = -ti.z;

    // A = pose * inv(node1)
    F3 ra = qrot(qp, ti);
    F3 tA{ tp.x + ra.x, tp.y + ra.y, tp.z + ra.z };
    F4 qA = qmul(qp, qi);

    // E = A * node2
    F3 rb = qrot(qA, t2);
    F3 tE{ tA.x + rb.x, tA.y + rb.y, tA.z + rb.z };
    F4 qE = qmul(qA, q2);

    // ---- se3_log ----
    if (qE.w < 0.f) { qE.x = -qE.x; qE.y = -qE.y; qE.z = -qE.z; qE.w = -qE.w; }
    const float n2q = qE.x * qE.x + qE.y * qE.y + qE.z * qE.z;
    const float nq = sqrtf(n2q);
    const float theta = 2.f * atan2f(nq, qE.w);
    const bool small = nq < 1e-6f;
    const float scale = small ? (2.f / fmaxf(qE.w, 1e-12f)) : (theta / nq);
    const F3 phi{ scale * qE.x, scale * qE.y, scale * qE.z };

    const float th2 = theta * theta;
    float coef;
    if (theta < 1e-4f) {
        coef = 1.f / 12.f + th2 / 720.f;
    } else {
        coef = 1.f / th2 - (1.f + cosf(theta)) / (2.f * theta * sinf(theta));
    }

    const F3 pxt  = cross3(phi, tE);
    const F3 ppxt = cross3(phi, pxt);
    o[0] = tE.x - 0.5f * pxt.x + coef * ppxt.x;
    o[1] = tE.y - 0.5f * pxt.y + coef * ppxt.y;
    o[2] = tE.z - 0.5f * pxt.z + coef * ppxt.z;
    o[3] = phi.x; o[4] = phi.y; o[5] = phi.z;
}

__global__ __launch_bounds__(BLK) void pose_graph_err_kernel(
    const float* __restrict__ nodes,   // [N_NODES, 7]
    const float* __restrict__ poses,   // [N_EDGES, 7]
    const int*   __restrict__ edges,   // [N_EDGES, 2] (int32)
    float*       __restrict__ out,     // [N_EDGES, 6]
    int n_edges)
{
    const long long t  = (long long)blockIdx.x * BLK + threadIdx.x;
    const long long e0 = t * EPT;
    if (e0 >= n_edges) return;

    if (e0 + EPT <= (long long)n_edges) {
        // ---- fast path: 4 consecutive edges, all loads issued up-front ----
        // poses: 4*28B = 112B starting at byte 112*t -> 7 aligned float4 loads
        union { float4 v[7]; float f[28]; } P;
        const float4* pv = (const float4*)(poses + e0 * 7);
        #pragma unroll
        for (int j = 0; j < 7; ++j) P.v[j] = pv[j];

        // edges: 4*8B = 32B at 32*t -> 2 aligned int4 loads
        union { int4 v[2]; int i[8]; } E;
        const int4* ev = (const int4*)(edges + e0 * 2);
        E.v[0] = ev[0]; E.v[1] = ev[1];

        // 8 independent node gathers, issued before any compute
        float nd[8][7];
        #pragma unroll
        for (int k = 0; k < 8; ++k) {
            const float* np = nodes + (size_t)E.i[k] * 7;
            #pragma unroll
            for (int j = 0; j < 7; ++j) nd[k][j] = np[j];
        }

        union { float4 v[6]; float f[24]; } O;
        #pragma unroll
        for (int k = 0; k < EPT; ++k) {
            F3 tp{ P.f[k*7+0], P.f[k*7+1], P.f[k*7+2] };
            F4 qp{ P.f[k*7+3], P.f[k*7+4], P.f[k*7+5], P.f[k*7+6] };
            edge_compute(tp, qp, nd[2*k], nd[2*k+1], &O.f[k*6]);
        }

        // out: 4*24B = 96B at 96*t -> 6 aligned float4 stores
        float4* ov = (float4*)(out + e0 * 6);
        #pragma unroll
        for (int j = 0; j < 6; ++j) ov[j] = O.v[j];
    } else {
        // ---- tail: scalar per-edge ----
        for (long long e = e0; e < (long long)n_edges; ++e) {
            const float* sp = poses + e * 7;
            F3 tp{ sp[0], sp[1], sp[2] };
            F4 qp{ sp[3], sp[4], sp[5], sp[6] };
            const int i1 = edges[e*2], i2 = edges[e*2+1];
            float o[6];
            edge_compute(tp, qp, nodes + (size_t)i1 * 7, nodes + (size_t)i2 * 7, o);
            #pragma unroll
            for (int j = 0; j < 6; ++j) out[e*6+j] = o[j];
        }
    }
}

extern "C" void kernel_launch(void* const* d_in, const int* in_sizes, int n_in,
                              void* d_out, int out_size, void* d_ws, size_t ws_size,
                              hipStream_t stream) {
    const float* nodes = (const float*)d_in[0];
    const float* poses = (const float*)d_in[1];
    const int*   edges = (const int*)d_in[2];
    float* out = (float*)d_out;

    const int n_edges = in_sizes[2] / 2;
    const int per_block = BLK * EPT;
    const int nblocks = (n_edges + per_block - 1) / per_block;
    pose_graph_err_kernel<<<nblocks, BLK, 0, stream>>>(nodes, poses, edges, out, n_edges);
}

// Round 3
// 124.457 us; speedup vs baseline: 1.1304x; 1.1304x over previous
//
#include <hip/hip_runtime.h>

constexpr int BLK = 256;
constexpr int EPT = 2;              // edges per thread
constexpr int EPB = BLK * EPT;      // 512 edges per block

struct F3 { float x, y, z; };
struct F4 { float x, y, z, w; };

__device__ __forceinline__ F3 cross3(const F3 a, const F3 b) {
    return { a.y * b.z - a.z * b.y,
             a.z * b.x - a.x * b.z,
             a.x * b.y - a.y * b.x };
}

__device__ __forceinline__ F3 qrot(const F4 q, const F3 v) {
    F3 qv{ q.x, q.y, q.z };
    F3 t = cross3(qv, v);
    t.x *= 2.f; t.y *= 2.f; t.z *= 2.f;
    F3 c = cross3(qv, t);
    return { v.x + q.w * t.x + c.x,
             v.y + q.w * t.y + c.y,
             v.z + q.w * t.z + c.z };
}

__device__ __forceinline__ F4 qmul(const F4 a, const F4 b) {
    return { a.w * b.x + a.x * b.w + a.y * b.z - a.z * b.y,
             a.w * b.y - a.x * b.z + a.y * b.w + a.z * b.x,
             a.w * b.z + a.x * b.y - a.y * b.x + a.z * b.w,
             a.w * b.w - a.x * b.x - a.y * b.y - a.z * b.z };
}

// full per-edge math given pose (tp,qp) and the two node records (8 floats each)
__device__ __forceinline__ void edge_compute(const F3 tp, const F4 qp,
                                             const float4 nA0, const float4 nA1,
                                             const float4 nB0, const float4 nB1,
                                             float* __restrict__ o)
{
    F3 t1{ nA0.x, nA0.y, nA0.z };
    F4 q1{ nA0.w, nA1.x, nA1.y, nA1.z };
    F3 t2{ nB0.x, nB0.y, nB0.z };
    F4 q2{ nB0.w, nB1.x, nB1.y, nB1.z };

    F4 qi{ -q1.x, -q1.y, -q1.z, q1.w };
    F3 ti = qrot(qi, t1);
    ti.x = -ti.x; ti.y = -ti.y; ti.z = -ti.z;

    F3 ra = qrot(qp, ti);
    F3 tA{ tp.x + ra.x, tp.y + ra.y, tp.z + ra.z };
    F4 qA = qmul(qp, qi);

    F3 rb = qrot(qA, t2);
    F3 tE{ tA.x + rb.x, tA.y + rb.y, tA.z + rb.z };
    F4 qE = qmul(qA, q2);

    if (qE.w < 0.f) { qE.x = -qE.x; qE.y = -qE.y; qE.z = -qE.z; qE.w = -qE.w; }
    const float n2q = qE.x * qE.x + qE.y * qE.y + qE.z * qE.z;
    const float nq = sqrtf(n2q);
    const float theta = 2.f * atan2f(nq, qE.w);
    const bool small = nq < 1e-6f;
    const float scale = small ? (2.f / fmaxf(qE.w, 1e-12f)) : (theta / nq);
    const F3 phi{ scale * qE.x, scale * qE.y, scale * qE.z };

    const float th2 = theta * theta;
    float coef;
    if (theta < 1e-4f) {
        coef = 1.f / 12.f + th2 / 720.f;
    } else {
        coef = 1.f / th2 - (1.f + cosf(theta)) / (2.f * theta * sinf(theta));
    }

    const F3 pxt  = cross3(phi, tE);
    const F3 ppxt = cross3(phi, pxt);
    o[0] = tE.x - 0.5f * pxt.x + coef * ppxt.x;
    o[1] = tE.y - 0.5f * pxt.y + coef * ppxt.y;
    o[2] = tE.z - 0.5f * pxt.z + coef * ppxt.z;
    o[3] = phi.x; o[4] = phi.y; o[5] = phi.z;
}

// ---- prep: pad nodes [N,7] -> ws [N,8] so each gather is 2 aligned float4 ----
__global__ __launch_bounds__(BLK) void pad_nodes_kernel(
    const float* __restrict__ nodes, float* __restrict__ ws, int n_nodes)
{
    int i = blockIdx.x * BLK + threadIdx.x;
    if (i < n_nodes) {
        const float* s = nodes + (size_t)i * 7;
        float4 a{ s[0], s[1], s[2], s[3] };
        float4 b{ s[4], s[5], s[6], 0.f };
        float4* d = (float4*)(ws + (size_t)i * 8);
        d[0] = a; d[1] = b;
    }
}

// NS = node record stride (8 = padded ws, 7 = raw fallback)
template<int NS>
__device__ __forceinline__ void load_node(const float* __restrict__ nodes, int idx,
                                          float4& a, float4& b)
{
    if (NS == 8) {
        const float4* g = (const float4*)(nodes + (size_t)idx * 8);
        a = g[0]; b = g[1];
    } else {
        const float* g = nodes + (size_t)idx * 7;
        a = { g[0], g[1], g[2], g[3] };
        b = { g[4], g[5], g[6], 0.f };
    }
}

template<int NS>
__global__ __launch_bounds__(BLK) void pose_graph_err_kernel(
    const float* __restrict__ nodes,   // stride NS
    const float* __restrict__ poses,   // [N_EDGES, 7]
    const int*   __restrict__ edges,   // [N_EDGES, 2] (int32)
    float*       __restrict__ out,     // [N_EDGES, 6]
    int n_edges)
{
    __shared__ float s_pose[EPB * 7];  // 14336 B

    const int tid = threadIdx.x;
    const long long bstart = (long long)blockIdx.x * EPB;
    const long long remain = (long long)n_edges - bstart;

    if (remain >= EPB) {
        // ---- stage poses: EPB*7 floats = 896 float4, fully coalesced ----
        const float4* pv = (const float4*)(poses + bstart * 7);
        float4* sp = (float4*)s_pose;
        #pragma unroll
        for (int i = tid; i < EPB * 7 / 4; i += BLK) sp[i] = pv[i];

        // ---- edges: 2 edges/thread = int4, aligned ----
        const long long e0 = bstart + (long long)tid * EPT;
        const int4 ij = *(const int4*)(edges + e0 * 2);

        // ---- issue all 4 node gathers (8 dwordx4) before compute ----
        float4 nA0, nA1, nB0, nB1, nC0, nC1, nD0, nD1;
        load_node<NS>(nodes, ij.x, nA0, nA1);
        load_node<NS>(nodes, ij.y, nB0, nB1);
        load_node<NS>(nodes, ij.z, nC0, nC1);
        load_node<NS>(nodes, ij.w, nD0, nD1);

        __syncthreads();

        // pose reads from LDS: 14 consecutive floats at word 14*tid
        // (stride 14, gcd(14,32)=2 -> 2-way bank alias, free)
        const float* p0 = s_pose + tid * 14;
        F3 tp0{ p0[0], p0[1], p0[2] };
        F4 qp0{ p0[3], p0[4], p0[5], p0[6] };
        F3 tp1{ p0[7], p0[8], p0[9] };
        F4 qp1{ p0[10], p0[11], p0[12], p0[13] };

        union { float4 v[3]; float f[12]; } O;
        edge_compute(tp0, qp0, nA0, nA1, nB0, nB1, &O.f[0]);
        edge_compute(tp1, qp1, nC0, nC1, nD0, nD1, &O.f[6]);

        // out: 12 floats at byte 48*global_thread -> 3 aligned float4 stores
        float4* ov = (float4*)(out + e0 * 6);
        ov[0] = O.v[0]; ov[1] = O.v[1]; ov[2] = O.v[2];
    } else {
        // ---- tail block: guarded scalar path, no staging ----
        for (int k = 0; k < EPT; ++k) {
            const long long e = bstart + tid + (long long)k * BLK;
            if (e < n_edges) {
                const float* sp = poses + e * 7;
                F3 tp{ sp[0], sp[1], sp[2] };
                F4 qp{ sp[3], sp[4], sp[5], sp[6] };
                float4 a0, a1, b0, b1;
                load_node<NS>(nodes, edges[e*2],   a0, a1);
                load_node<NS>(nodes, edges[e*2+1], b0, b1);
                float o[6];
                edge_compute(tp, qp, a0, a1, b0, b1, o);
                #pragma unroll
                for (int j = 0; j < 6; ++j) out[e*6+j] = o[j];
            }
        }
    }
}

extern "C" void kernel_launch(void* const* d_in, const int* in_sizes, int n_in,
                              void* d_out, int out_size, void* d_ws, size_t ws_size,
                              hipStream_t stream) {
    const float* nodes = (const float*)d_in[0];
    const float* poses = (const float*)d_in[1];
    const int*   edges = (const int*)d_in[2];
    float* out = (float*)d_out;

    const int n_nodes = in_sizes[0] / 7;
    const int n_edges = in_sizes[2] / 2;
    const int nblocks = (n_edges + EPB - 1) / EPB;

    const size_t pad_bytes = (size_t)n_nodes * 8 * sizeof(float);
    if (ws_size >= pad_bytes) {
        float* nodes8 = (float*)d_ws;
        pad_nodes_kernel<<<(n_nodes + BLK - 1) / BLK, BLK, 0, stream>>>(nodes, nodes8, n_nodes);
        pose_graph_err_kernel<8><<<nblocks, BLK, 0, stream>>>(nodes8, poses, edges, out, n_edges);
    } else {
        pose_graph_err_kernel<7><<<nblocks, BLK, 0, stream>>>(nodes, poses, edges, out, n_edges);
    }
}

// Round 4
// 115.458 us; speedup vs baseline: 1.2185x; 1.0779x over previous
//
#include <hip/hip_runtime.h>

constexpr int BLK = 256;

struct F3 { float x, y, z; };
struct F4 { float x, y, z, w; };

__device__ __forceinline__ F3 cross3(const F3 a, const F3 b) {
    return { a.y * b.z - a.z * b.y,
             a.z * b.x - a.x * b.z,
             a.x * b.y - a.y * b.x };
}

// v + w*t + cross(qv, t), t = 2*cross(qv, v)   (matches _qrot)
__device__ __forceinline__ F3 qrot(const F4 q, const F3 v) {
    F3 qv{ q.x, q.y, q.z };
    F3 t = cross3(qv, v);
    t.x *= 2.f; t.y *= 2.f; t.z *= 2.f;
    F3 c = cross3(qv, t);
    return { v.x + q.w * t.x + c.x,
             v.y + q.w * t.y + c.y,
             v.z + q.w * t.z + c.z };
}

__device__ __forceinline__ F4 qmul(const F4 a, const F4 b) {
    return { a.w * b.x + a.x * b.w + a.y * b.z - a.z * b.y,
             a.w * b.y - a.x * b.z + a.y * b.w + a.z * b.x,
             a.w * b.z + a.x * b.y - a.y * b.x + a.z * b.w,
             a.w * b.w - a.x * b.x - a.y * b.y - a.z * b.z };
}

__device__ __forceinline__ void edge_compute(const F3 tp, const F4 qp,
                                             const float4 nA0, const float4 nA1,
                                             const float4 nB0, const float4 nB1,
                                             float* __restrict__ o)
{
    F3 t1{ nA0.x, nA0.y, nA0.z };
    F4 q1{ nA0.w, nA1.x, nA1.y, nA1.z };
    F3 t2{ nB0.x, nB0.y, nB0.z };
    F4 q2{ nB0.w, nB1.x, nB1.y, nB1.z };

    // inv(node1)
    F4 qi{ -q1.x, -q1.y, -q1.z, q1.w };
    F3 ti = qrot(qi, t1);
    ti.x = -ti.x; ti.y = -ti.y; ti.z = -ti.z;

    // A = pose * inv(node1)
    F3 ra = qrot(qp, ti);
    F3 tA{ tp.x + ra.x, tp.y + ra.y, tp.z + ra.z };
    F4 qA = qmul(qp, qi);

    // E = A * node2
    F3 rb = qrot(qA, t2);
    F3 tE{ tA.x + rb.x, tA.y + rb.y, tA.z + rb.z };
    F4 qE = qmul(qA, q2);

    // ---- se3_log (trig-free coef) ----
    if (qE.w < 0.f) { qE.x = -qE.x; qE.y = -qE.y; qE.z = -qE.z; qE.w = -qE.w; }
    const float n2q = qE.x * qE.x + qE.y * qE.y + qE.z * qE.z;
    const float nq = sqrtf(n2q);
    const float theta = 2.f * atan2f(nq, qE.w);

    const float scale = (nq < 1e-6f) ? (2.f / fmaxf(qE.w, 1e-12f)) : (theta / nq);
    const F3 phi{ scale * qE.x, scale * qE.y, scale * qE.z };

    // theta = 2*atan2(n,w)  =>  cos th = (w^2-n^2)/s, sin th = 2nw/s, s = n^2+w^2
    // => (1+cos th)/(2 th sin th) = w/(2 th n), exactly (s cancels).
    const float th2 = theta * theta;
    const float coef = (theta < 1e-4f)
        ? (1.f / 12.f + th2 / 720.f)
        : (1.f / th2 - qE.w / (2.f * theta * nq));

    const F3 pxt  = cross3(phi, tE);
    const F3 ppxt = cross3(phi, pxt);
    o[0] = tE.x - 0.5f * pxt.x + coef * ppxt.x;
    o[1] = tE.y - 0.5f * pxt.y + coef * ppxt.y;
    o[2] = tE.z - 0.5f * pxt.z + coef * ppxt.z;
    o[3] = phi.x; o[4] = phi.y; o[5] = phi.z;
}

// ---- prep: pad nodes [N,7] -> ws [N,8]: each gather = 2 aligned dwordx4 ----
__global__ __launch_bounds__(BLK) void pad_nodes_kernel(
    const float* __restrict__ nodes, float* __restrict__ ws, int n_nodes)
{
    int i = blockIdx.x * BLK + threadIdx.x;
    if (i < n_nodes) {
        const float* s = nodes + (size_t)i * 7;
        float4 a{ s[0], s[1], s[2], s[3] };
        float4 b{ s[4], s[5], s[6], 0.f };
        float4* d = (float4*)(ws + (size_t)i * 8);
        d[0] = a; d[1] = b;
    }
}

template<int NS>  // node record stride: 8 (padded) or 7 (fallback)
__device__ __forceinline__ void load_node(const float* __restrict__ nodes, int idx,
                                          float4& a, float4& b)
{
    if (NS == 8) {
        const float4* g = (const float4*)(nodes + (size_t)idx * 8);
        a = g[0]; b = g[1];
    } else {
        const float* g = nodes + (size_t)idx * 7;
        a = { g[0], g[1], g[2], g[3] };
        b = { g[4], g[5], g[6], 0.f };
    }
}

template<int NS>
__global__ __launch_bounds__(BLK) void pose_graph_err_kernel(
    const float* __restrict__ nodes,   // stride NS
    const float* __restrict__ poses,   // [N_EDGES, 7]
    const int*   __restrict__ edges,   // [N_EDGES, 2] (int32)
    float*       __restrict__ out,     // [N_EDGES, 6]
    int n_edges)
{
    __shared__ float s_pose[BLK * 7];  // 7168 B
    __shared__ float s_out [BLK * 6];  // 6144 B

    const int tid = threadIdx.x;
    const int bstart = blockIdx.x * BLK;
    const int cnt = min(BLK, n_edges - bstart);

    // ---- issue gathers early (overlap with pose staging) ----
    float4 a0, a1, b0, b1;
    if (tid < cnt) {
        const int2 ij = ((const int2*)edges)[bstart + tid];
        load_node<NS>(nodes, ij.x, a0, a1);
        load_node<NS>(nodes, ij.y, b0, b1);
    }

    // ---- stage poses: coalesced float4 when block is full ----
    if (cnt == BLK) {
        const float4* pv = (const float4*)(poses + (size_t)bstart * 7);
        float4* sp = (float4*)s_pose;
        #pragma unroll
        for (int i = tid; i < BLK * 7 / 4; i += BLK) sp[i] = pv[i];
    } else {
        for (int i = tid; i < cnt * 7; i += BLK)
            s_pose[i] = poses[(size_t)bstart * 7 + i];
    }
    __syncthreads();

    if (tid < cnt) {
        // stride-7 LDS reads: bank = (7*tid + i) % 32, gcd(7,32)=1 -> conflict-free
        const float* sp = s_pose + tid * 7;
        F3 tp{ sp[0], sp[1], sp[2] };
        F4 qp{ sp[3], sp[4], sp[5], sp[6] };

        float o[6];
        edge_compute(tp, qp, a0, a1, b0, b1, o);

        float* so = s_out + tid * 6;
        #pragma unroll
        for (int j = 0; j < 6; ++j) so[j] = o[j];
    }
    __syncthreads();

    // ---- coalesced float4 store of the block's output ----
    if (cnt == BLK) {
        float4* ov = (float4*)(out + (size_t)bstart * 6);
        const float4* sv = (const float4*)s_out;
        #pragma unroll
        for (int i = tid; i < BLK * 6 / 4; i += BLK) ov[i] = sv[i];
    } else {
        for (int i = tid; i < cnt * 6; i += BLK)
            out[(size_t)bstart * 6 + i] = s_out[i];
    }
}

extern "C" void kernel_launch(void* const* d_in, const int* in_sizes, int n_in,
                              void* d_out, int out_size, void* d_ws, size_t ws_size,
                              hipStream_t stream) {
    const float* nodes = (const float*)d_in[0];
    const float* poses = (const float*)d_in[1];
    const int*   edges = (const int*)d_in[2];
    float* out = (float*)d_out;

    const int n_nodes = in_sizes[0] / 7;
    const int n_edges = in_sizes[2] / 2;
    const int nblocks = (n_edges + BLK - 1) / BLK;

    const size_t pad_bytes = (size_t)n_nodes * 8 * sizeof(float);
    if (ws_size >= pad_bytes) {
        float* nodes8 = (float*)d_ws;
        pad_nodes_kernel<<<(n_nodes + BLK - 1) / BLK, BLK, 0, stream>>>(nodes, nodes8, n_nodes);
        pose_graph_err_kernel<8><<<nblocks, BLK, 0, stream>>>(nodes8, poses, edges, out, n_edges);
    } else {
        pose_graph_err_kernel<7><<<nblocks, BLK, 0, stream>>>(nodes, poses, edges, out, n_edges);
    }
}